// Round 5
// baseline (336.366 us; speedup 1.0000x reference)
//
#include <hip/hip_runtime.h>

#define B_  4
#define C_  16
#define H_  256
#define W_  256
#define CO_ 16
#define KS_ 3
#define KK_ 9
#define HW_ (H_ * W_)
#define KER_OFF ((size_t)B_ * HW_ * C_)   // float offset of t_ker inside ws

// ------- Kernel 1: NCHW -> NHWC transpose + ker transpose into workspace ---
__global__ __launch_bounds__(256) void transpose_nhwc(
    const float* __restrict__ inp, const float* __restrict__ ker,
    float* __restrict__ wsp)
{
    __shared__ float tile[256][C_ + 1];
    const int base = blockIdx.x * 256;      // flat (b*HW + hw) base
    const int t    = threadIdx.x;
    const int e    = base + t;
    const int b    = e >> 16;
    const int hw   = e & (HW_ - 1);
    const float* src = inp + (size_t)b * (C_ * HW_) + hw;
#pragma unroll
    for (int c = 0; c < C_; c++)
        tile[t][c] = src[c * HW_];          // coalesced reads per c-plane
    __syncthreads();
    float4* dst = (float4*)(wsp + (size_t)base * C_);
#pragma unroll
    for (int q = 0; q < 4; q++) {
        const int f   = q * 256 + t;
        const int hwl = f >> 2;
        const int c0  = (f & 3) * 4;
        dst[f] = make_float4(tile[hwl][c0], tile[hwl][c0 + 1],
                             tile[hwl][c0 + 2], tile[hwl][c0 + 3]);
    }
    if (blockIdx.x == 0) {
        // t_ker[kk*256 + c*16 + o] = ker[(o*16+c)*9 + kk]  (tiny: 2304 elems)
        for (int i = t; i < KK_ * C_ * CO_; i += 256) {
            const int kk = i >> 8;
            const int c  = (i >> 4) & 15;
            const int o  = i & 15;
            wsp[KER_OFF + i] = ker[(o * C_ + c) * KK_ + kk];
        }
    }
}

// ------- tap address/weight setup ------------------------------------------
__device__ __forceinline__ void tap_setup(
    int h, int w, int kk, float dy, float dx, const float* inb,
    const float4** p, float* wt)
{
    const float y = dy + (float)(h - 1 + kk / KS_);
    const float x = dx + (float)(w - 1 + kk % KS_);
    const float y0f = floorf(y);
    const float x0f = floorf(x);
    const int   y0  = (int)y0f;
    const int   x0  = (int)x0f;
    const float wy  = y - y0f;
    const float wx  = x - x0f;

    float w00 = (1.f - wy) * (1.f - wx);
    float w01 = (1.f - wy) * wx;
    float w10 = wy * (1.f - wx);
    float w11 = wy * wx;

    const bool v0y = ((unsigned)y0       < (unsigned)H_);
    const bool v1y = ((unsigned)(y0 + 1) < (unsigned)H_);
    const bool v0x = ((unsigned)x0       < (unsigned)W_);
    const bool v1x = ((unsigned)(x0 + 1) < (unsigned)W_);

    wt[0] = (v0y & v0x) ? w00 : 0.f;
    wt[1] = (v0y & v1x) ? w01 : 0.f;
    wt[2] = (v1y & v0x) ? w10 : 0.f;
    wt[3] = (v1y & v1x) ? w11 : 0.f;

    const int y0c = min(max(y0,     0), H_ - 1);
    const int y1c = min(max(y0 + 1, 0), H_ - 1);
    const int x0c = min(max(x0,     0), W_ - 1);
    const int x1c = min(max(x0 + 1, 0), W_ - 1);

    p[0] = (const float4*)(inb + (size_t)(y0c * W_ + x0c) * C_);
    p[1] = (const float4*)(inb + (size_t)(y0c * W_ + x1c) * C_);
    p[2] = (const float4*)(inb + (size_t)(y1c * W_ + x0c) * C_);
    p[3] = (const float4*)(inb + (size_t)(y1c * W_ + x1c) * C_);
}

// ------- Kernel 2: deform-conv + MSE, software-pipelined NHWC gathers ------
__global__ __launch_bounds__(256, 4) void deform_loss_nhwc(
    const float* __restrict__ off, const float* __restrict__ wsp,
    const float* __restrict__ tgt, float* __restrict__ out)
{
    // XCD swizzle: bijection on [0,1024); xcd = blk&7 gets a contiguous
    // 128-row span so row re-reads hit the same per-XCD L2.
    const int bh = (blockIdx.x & 7) * 128 + (blockIdx.x >> 3);
    const int b  = bh >> 8;
    const int h  = bh & (H_ - 1);
    const int w  = threadIdx.x;
    const int hw = h * W_ + w;

    const float* offb = off + (size_t)b * (2 * KK_ * HW_) + hw;
    const float* inb  = wsp + (size_t)b * (HW_ * C_);
    const float* tker = wsp + KER_OFF;

    float acc[CO_];
#pragma unroll
    for (int o = 0; o < CO_; o++) acc[o] = 0.f;

    const float4* p[4];
    float wt[4];
    float4 buf[16];

    // prologue: issue tap 0's 16 corner loads
    {
        const float dy = offb[0];
        const float dx = offb[HW_];
        tap_setup(h, w, 0, dy, dx, inb, p, wt);
#pragma unroll
        for (int q = 0; q < 4; q++) {
            buf[q]      = p[0][q];
            buf[4 + q]  = p[1][q];
            buf[8 + q]  = p[2][q];
            buf[12 + q] = p[3][q];
        }
    }

#pragma unroll 1
    for (int kk = 0; kk < KK_; kk++) {
        float dyN = 0.f, dxN = 0.f;
        if (kk + 1 < KK_) {
            dyN = offb[(2 * kk + 2) * HW_];
            dxN = offb[(2 * kk + 3) * HW_];
        }

        // consume buf -> sc (frees buf for the next tap's prefetch)
        float sc[C_];
#pragma unroll
        for (int q = 0; q < 4; q++) {
            const float4 a  = buf[q];
            const float4 bq = buf[4 + q];
            const float4 cq = buf[8 + q];
            const float4 dq = buf[12 + q];
            sc[q * 4 + 0] = a.x * wt[0] + bq.x * wt[1] + cq.x * wt[2] + dq.x * wt[3];
            sc[q * 4 + 1] = a.y * wt[0] + bq.y * wt[1] + cq.y * wt[2] + dq.y * wt[3];
            sc[q * 4 + 2] = a.z * wt[0] + bq.z * wt[1] + cq.z * wt[2] + dq.z * wt[3];
            sc[q * 4 + 3] = a.w * wt[0] + bq.w * wt[1] + cq.w * wt[2] + dq.w * wt[3];
        }

        // prefetch tap kk+1 — in flight during the 256-FMA accumulate below
        if (kk + 1 < KK_) {
            tap_setup(h, w, kk + 1, dyN, dxN, inb, p, wt);
#pragma unroll
            for (int q = 0; q < 4; q++) {
                buf[q]      = p[0][q];
                buf[4 + q]  = p[1][q];
                buf[8 + q]  = p[2][q];
                buf[12 + q] = p[3][q];
            }
        }

        // accumulate: ker is lane-invariant -> s_load broadcasts
        const float* kt = tker + kk * (C_ * CO_);
#pragma unroll
        for (int c = 0; c < C_; c++) {
            const float s = sc[c];
#pragma unroll
            for (int o = 0; o < CO_; o++)
                acc[o] = fmaf(s, kt[c * 16 + o], acc[o]);
        }
    }

    const float* tb = tgt + (size_t)b * (CO_ * HW_) + hw;
    float part = 0.f;
#pragma unroll
    for (int o = 0; o < CO_; o++) {
        const float d = acc[o] - tb[o * HW_];
        part = fmaf(d, d, part);
    }
    part *= (1.0f / (float)((size_t)B_ * CO_ * HW_));

#pragma unroll
    for (int s = 32; s > 0; s >>= 1)
        part += __shfl_down(part, s, 64);
    if ((threadIdx.x & 63) == 0)
        atomicAdd(out, part);
}

// ------- Fallback (round-1 NCHW kernel, used if ws too small) --------------
__global__ __launch_bounds__(256) void deform_loss_kernel(
    const float* __restrict__ off, const float* __restrict__ inp,
    const float* __restrict__ ker, const float* __restrict__ tgt,
    float* __restrict__ out)
{
    const int idx = blockIdx.x * blockDim.x + threadIdx.x;
    float part = 0.f;
    if (idx < B_ * H_ * W_) {
        const int w  = idx & (W_ - 1);
        const int h  = (idx >> 8) & (H_ - 1);
        const int b  = idx >> 16;
        const int hw = h * W_ + w;
        const float* offb = off + (size_t)b * (2 * KK_ * HW_);
        const float* inpb = inp + (size_t)b * (C_ * HW_);
        float acc[CO_];
#pragma unroll
        for (int o = 0; o < CO_; o++) acc[o] = 0.f;
        for (int kk = 0; kk < KK_; kk++) {
            const float dy = offb[(2 * kk)     * HW_ + hw];
            const float dx = offb[(2 * kk + 1) * HW_ + hw];
            const float y = dy + (float)(h - 1 + kk / KS_);
            const float x = dx + (float)(w - 1 + kk % KS_);
            const float y0f = floorf(y);
            const float x0f = floorf(x);
            const int   y0  = (int)y0f;
            const int   x0  = (int)x0f;
            const float wy  = y - y0f;
            const float wx  = x - x0f;
            float w00 = (1.f - wy) * (1.f - wx);
            float w01 = (1.f - wy) * wx;
            float w10 = wy * (1.f - wx);
            float w11 = wy * wx;
            const bool v0y = ((unsigned)y0       < (unsigned)H_);
            const bool v1y = ((unsigned)(y0 + 1) < (unsigned)H_);
            const bool v0x = ((unsigned)x0       < (unsigned)W_);
            const bool v1x = ((unsigned)(x0 + 1) < (unsigned)W_);
            w00 = (v0y & v0x) ? w00 : 0.f;
            w01 = (v0y & v1x) ? w01 : 0.f;
            w10 = (v1y & v0x) ? w10 : 0.f;
            w11 = (v1y & v1x) ? w11 : 0.f;
            const int i00 = min(max(y0,0),H_-1)*W_ + min(max(x0,0),W_-1);
            const int i01 = min(max(y0,0),H_-1)*W_ + min(max(x0+1,0),W_-1);
            const int i10 = min(max(y0+1,0),H_-1)*W_ + min(max(x0,0),W_-1);
            const int i11 = min(max(y0+1,0),H_-1)*W_ + min(max(x0+1,0),W_-1);
            for (int c = 0; c < C_; c++) {
                const float* pp = inpb + c * HW_;
                const float s = pp[i00]*w00 + pp[i01]*w01 + pp[i10]*w10 + pp[i11]*w11;
#pragma unroll
                for (int o = 0; o < CO_; o++)
                    acc[o] = fmaf(s, ker[(o * C_ + c) * KK_ + kk], acc[o]);
            }
        }
        const float* tb = tgt + (size_t)b * (CO_ * HW_);
#pragma unroll
        for (int o = 0; o < CO_; o++) {
            const float d = acc[o] - tb[o * HW_ + hw];
            part = fmaf(d, d, part);
        }
        part *= (1.0f / (float)((size_t)B_ * CO_ * HW_));
    }
#pragma unroll
    for (int s = 32; s > 0; s >>= 1)
        part += __shfl_down(part, s, 64);
    if ((threadIdx.x & 63) == 0)
        atomicAdd(out, part);
}

extern "C" void kernel_launch(void* const* d_in, const int* in_sizes, int n_in,
                              void* d_out, int out_size, void* d_ws, size_t ws_size,
                              hipStream_t stream) {
    const float* offsets = (const float*)d_in[0];
    const float* input   = (const float*)d_in[1];
    const float* ker     = (const float*)d_in[2];
    const float* target  = (const float*)d_in[3];
    float* out = (float*)d_out;

    hipMemsetAsync(out, 0, sizeof(float), stream);

    const size_t need = (KER_OFF + (size_t)KK_ * C_ * CO_) * sizeof(float);
    if (ws_size >= need) {
        float* wsp = (float*)d_ws;
        transpose_nhwc<<<(B_ * HW_) / 256, 256, 0, stream>>>(input, ker, wsp);
        deform_loss_nhwc<<<B_ * H_, 256, 0, stream>>>(offsets, wsp, target, out);
    } else {
        const int total = B_ * H_ * W_;
        deform_loss_kernel<<<(total + 255) / 256, 256, 0, stream>>>(
            offsets, input, ker, target, out);
    }
}

// Round 6
// 314.697 us; speedup vs baseline: 1.0689x; 1.0689x over previous
//
#include <hip/hip_runtime.h>

#define B_  4
#define C_  16
#define H_  256
#define W_  256
#define CO_ 16
#define KS_ 3
#define KK_ 9
#define HW_ (H_ * W_)
#define KER_OFF ((size_t)B_ * HW_ * C_)   // float offset of t_ker inside ws

// ------- Kernel 1: NCHW -> NHWC transpose + ker transpose into workspace ---
__global__ __launch_bounds__(256) void transpose_nhwc(
    const float* __restrict__ inp, const float* __restrict__ ker,
    float* __restrict__ wsp)
{
    __shared__ float tile[256][C_ + 1];
    const int base = blockIdx.x * 256;      // flat (b*HW + hw) base
    const int t    = threadIdx.x;
    const int e    = base + t;
    const int b    = e >> 16;
    const int hw   = e & (HW_ - 1);
    const float* src = inp + (size_t)b * (C_ * HW_) + hw;
#pragma unroll
    for (int c = 0; c < C_; c++)
        tile[t][c] = src[c * HW_];          // coalesced reads per c-plane
    __syncthreads();
    float4* dst = (float4*)(wsp + (size_t)base * C_);
#pragma unroll
    for (int q = 0; q < 4; q++) {
        const int f   = q * 256 + t;
        const int hwl = f >> 2;
        const int c0  = (f & 3) * 4;
        dst[f] = make_float4(tile[hwl][c0], tile[hwl][c0 + 1],
                             tile[hwl][c0 + 2], tile[hwl][c0 + 3]);
    }
    if (blockIdx.x == 0) {
        // t_ker[kk*256 + c*16 + o] = ker[(o*16+c)*9 + kk]
        for (int i = t; i < KK_ * C_ * CO_; i += 256) {
            const int kk = i >> 8;
            const int c  = (i >> 4) & 15;
            const int o  = i & 15;
            wsp[KER_OFF + i] = ker[(o * C_ + c) * KK_ + kk];
        }
    }
}

// ------- Kernel 2: quad-cooperative deform-conv + MSE ----------------------
// Wave = 16 pixels x 4 channel-quad lanes. Corner loads: 4 lanes cover one
// full 64B pixel-line -> 16 lines/instruction (the TA floor).
__global__ __launch_bounds__(256, 4) void deform_loss_quad(
    const float* __restrict__ off, const float* __restrict__ wsp,
    const float* __restrict__ tgt, float* __restrict__ out)
{
    __shared__ float skt[KK_ * C_ * CO_];   // 9216 B, [kk][c][o]
    for (int i = threadIdx.x; i < KK_ * C_ * CO_; i += 256)
        skt[i] = wsp[KER_OFF + i];
    __syncthreads();

    // XCD swizzle: bijection on [0,4096); each XCD gets 512 consecutive
    // 64-pixel blocks = 128 contiguous rows -> per-XCD L2 locality.
    const int f   = (blockIdx.x & 7) * 512 + (blockIdx.x >> 3);
    const int t    = threadIdx.x;
    const int lane = t & 63;
    const int q    = lane >> 4;              // channel quad (0..3)
    const int pl   = lane & 15;              // pixel within wave
    const int pix  = f * 64 + (t >> 6) * 16 + pl;
    const int b    = pix >> 16;
    const int hw   = pix & (HW_ - 1);
    const int h    = hw >> 8;
    const int w    = hw & (W_ - 1);

    const float* offb = off + (size_t)b * (2 * KK_ * HW_) + hw;
    const float4* base = (const float4*)(wsp + (size_t)b * (HW_ * C_));

    // hoist all 18 offset loads (independent; kills per-tap chain head)
    float dyv[KK_], dxv[KK_];
#pragma unroll
    for (int kk = 0; kk < KK_; kk++) {
        dyv[kk] = offb[(2 * kk)     * HW_];
        dxv[kk] = offb[(2 * kk + 1) * HW_];
    }

    float acc[CO_];
#pragma unroll
    for (int o = 0; o < CO_; o++) acc[o] = 0.f;

#pragma unroll
    for (int kk = 0; kk < KK_; kk++) {
        const float y = dyv[kk] + (float)(h - 1 + kk / KS_);
        const float x = dxv[kk] + (float)(w - 1 + kk % KS_);

        const float y0f = floorf(y);
        const float x0f = floorf(x);
        const int   y0  = (int)y0f;
        const int   x0  = (int)x0f;
        const float wy  = y - y0f;
        const float wx  = x - x0f;

        float w00 = (1.f - wy) * (1.f - wx);
        float w01 = (1.f - wy) * wx;
        float w10 = wy * (1.f - wx);
        float w11 = wy * wx;

        const bool v0y = ((unsigned)y0       < (unsigned)H_);
        const bool v1y = ((unsigned)(y0 + 1) < (unsigned)H_);
        const bool v0x = ((unsigned)x0       < (unsigned)W_);
        const bool v1x = ((unsigned)(x0 + 1) < (unsigned)W_);

        w00 = (v0y & v0x) ? w00 : 0.f;
        w01 = (v0y & v1x) ? w01 : 0.f;
        w10 = (v1y & v0x) ? w10 : 0.f;
        w11 = (v1y & v1x) ? w11 : 0.f;

        const int y0c = min(max(y0,     0), H_ - 1);
        const int y1c = min(max(y0 + 1, 0), H_ - 1);
        const int x0c = min(max(x0,     0), W_ - 1);
        const int x1c = min(max(x0 + 1, 0), W_ - 1);

        // quad-cooperative: lane reads ITS 16B quarter of each corner line
        const float4 a4 = base[(y0c * W_ + x0c) * 4 + q];
        const float4 b4 = base[(y0c * W_ + x1c) * 4 + q];
        const float4 c4 = base[(y1c * W_ + x0c) * 4 + q];
        const float4 d4 = base[(y1c * W_ + x1c) * 4 + q];

        float s[4];
        s[0] = a4.x * w00 + b4.x * w01 + c4.x * w10 + d4.x * w11;
        s[1] = a4.y * w00 + b4.y * w01 + c4.y * w10 + d4.y * w11;
        s[2] = a4.z * w00 + b4.z * w01 + c4.z * w10 + d4.z * w11;
        s[3] = a4.w * w00 + b4.w * w01 + c4.w * w10 + d4.w * w11;

        // kt addresses depend only on q -> 4-address broadcast LDS reads
        const float* kb = skt + kk * (C_ * CO_) + q * 4 * CO_;
#pragma unroll
        for (int j = 0; j < 4; j++) {
            const float sj = s[j];
            const float4* k4 = (const float4*)(kb + j * CO_);
#pragma unroll
            for (int og = 0; og < 4; og++) {
                const float4 kv = k4[og];
                acc[og * 4 + 0] = fmaf(sj, kv.x, acc[og * 4 + 0]);
                acc[og * 4 + 1] = fmaf(sj, kv.y, acc[og * 4 + 1]);
                acc[og * 4 + 2] = fmaf(sj, kv.z, acc[og * 4 + 2]);
                acc[og * 4 + 3] = fmaf(sj, kv.w, acc[og * 4 + 3]);
            }
        }
    }

    // quad butterfly: sum channel-quad partials (lanes l, l^16, l^32, l^48)
#pragma unroll
    for (int o = 0; o < CO_; o++) {
        acc[o] += __shfl_xor(acc[o], 16, 64);
        acc[o] += __shfl_xor(acc[o], 32, 64);
    }

    // each lane handles its o-quad of its pixel
    const float* tb = tgt + (size_t)b * (CO_ * HW_) + hw;
    float part = 0.f;
#pragma unroll
    for (int j = 0; j < 4; j++) {
        const int o = q * 4 + j;
        const float d = acc[o] - tb[o * HW_];
        part = fmaf(d, d, part);
    }
    part *= (1.0f / (float)((size_t)B_ * CO_ * HW_));

#pragma unroll
    for (int sft = 32; sft > 0; sft >>= 1)
        part += __shfl_down(part, sft, 64);
    if (lane == 0)
        atomicAdd(out, part);
}

// ------- Fallback (round-1 NCHW kernel, used if ws too small) --------------
__global__ __launch_bounds__(256) void deform_loss_kernel(
    const float* __restrict__ off, const float* __restrict__ inp,
    const float* __restrict__ ker, const float* __restrict__ tgt,
    float* __restrict__ out)
{
    const int idx = blockIdx.x * blockDim.x + threadIdx.x;
    float part = 0.f;
    if (idx < B_ * H_ * W_) {
        const int w  = idx & (W_ - 1);
        const int h  = (idx >> 8) & (H_ - 1);
        const int b  = idx >> 16;
        const int hw = h * W_ + w;
        const float* offb = off + (size_t)b * (2 * KK_ * HW_);
        const float* inpb = inp + (size_t)b * (C_ * HW_);
        float acc[CO_];
#pragma unroll
        for (int o = 0; o < CO_; o++) acc[o] = 0.f;
        for (int kk = 0; kk < KK_; kk++) {
            const float dy = offb[(2 * kk)     * HW_ + hw];
            const float dx = offb[(2 * kk + 1) * HW_ + hw];
            const float y = dy + (float)(h - 1 + kk / KS_);
            const float x = dx + (float)(w - 1 + kk % KS_);
            const float y0f = floorf(y);
            const float x0f = floorf(x);
            const int   y0  = (int)y0f;
            const int   x0  = (int)x0f;
            const float wy  = y - y0f;
            const float wx  = x - x0f;
            float w00 = (1.f - wy) * (1.f - wx);
            float w01 = (1.f - wy) * wx;
            float w10 = wy * (1.f - wx);
            float w11 = wy * wx;
            const bool v0y = ((unsigned)y0       < (unsigned)H_);
            const bool v1y = ((unsigned)(y0 + 1) < (unsigned)H_);
            const bool v0x = ((unsigned)x0       < (unsigned)W_);
            const bool v1x = ((unsigned)(x0 + 1) < (unsigned)W_);
            w00 = (v0y & v0x) ? w00 : 0.f;
            w01 = (v0y & v1x) ? w01 : 0.f;
            w10 = (v1y & v0x) ? w10 : 0.f;
            w11 = (v1y & v1x) ? w11 : 0.f;
            const int i00 = min(max(y0,0),H_-1)*W_ + min(max(x0,0),W_-1);
            const int i01 = min(max(y0,0),H_-1)*W_ + min(max(x0+1,0),W_-1);
            const int i10 = min(max(y0+1,0),H_-1)*W_ + min(max(x0,0),W_-1);
            const int i11 = min(max(y0+1,0),H_-1)*W_ + min(max(x0+1,0),W_-1);
            for (int c = 0; c < C_; c++) {
                const float* pp = inpb + c * HW_;
                const float s = pp[i00]*w00 + pp[i01]*w01 + pp[i10]*w10 + pp[i11]*w11;
#pragma unroll
                for (int o = 0; o < CO_; o++)
                    acc[o] = fmaf(s, ker[(o * C_ + c) * KK_ + kk], acc[o]);
            }
        }
        const float* tb = tgt + (size_t)b * (CO_ * HW_);
#pragma unroll
        for (int o = 0; o < CO_; o++) {
            const float d = acc[o] - tb[o * HW_ + hw];
            part = fmaf(d, d, part);
        }
        part *= (1.0f / (float)((size_t)B_ * CO_ * HW_));
    }
#pragma unroll
    for (int sft = 32; sft > 0; sft >>= 1)
        part += __shfl_down(part, sft, 64);
    if ((threadIdx.x & 63) == 0)
        atomicAdd(out, part);
}

extern "C" void kernel_launch(void* const* d_in, const int* in_sizes, int n_in,
                              void* d_out, int out_size, void* d_ws, size_t ws_size,
                              hipStream_t stream) {
    const float* offsets = (const float*)d_in[0];
    const float* input   = (const float*)d_in[1];
    const float* ker     = (const float*)d_in[2];
    const float* target  = (const float*)d_in[3];
    float* out = (float*)d_out;

    hipMemsetAsync(out, 0, sizeof(float), stream);

    const size_t need = (KER_OFF + (size_t)KK_ * C_ * CO_) * sizeof(float);
    if (ws_size >= need) {
        float* wsp = (float*)d_ws;
        transpose_nhwc<<<(B_ * HW_) / 256, 256, 0, stream>>>(input, ker, wsp);
        // 4096 blocks of 256 threads; each block = 64 consecutive pixels,
        // each wave = 16 pixels x 4 channel-quad lanes
        deform_loss_quad<<<(B_ * HW_) / 64, 256, 0, stream>>>(offsets, wsp, target, out);
    } else {
        const int total = B_ * H_ * W_;
        deform_loss_kernel<<<(total + 255) / 256, 256, 0, stream>>>(
            offsets, input, ker, target, out);
    }
}

// Round 7
// 161.867 us; speedup vs baseline: 2.0780x; 1.9442x over previous
//
#include <hip/hip_runtime.h>

#define B_  4
#define C_  16
#define H_  256
#define W_  256
#define CO_ 16
#define KS_ 3
#define KK_ 9
#define HW_ (H_ * W_)
// ws layout: [0, 8MB) bf16 NHWC image (as u32 words), then fp32 t_ker
#define IMG_WORDS ((size_t)B_ * HW_ * 8)        // 2,097,152 u32 words
#define KER_OFF   IMG_WORDS                     // float offset of t_ker

#define LOBF(u) __uint_as_float((u) << 16)
#define HIBF(u) __uint_as_float((u) & 0xffff0000u)

__device__ __forceinline__ unsigned rne_bf16(float v) {
    unsigned b = __float_as_uint(v);
    return (b + 0x7fffu + ((b >> 16) & 1u)) >> 16;
}

// ------- Kernel 1: NCHW fp32 -> NHWC bf16 pack + ker transpose -------------
__global__ __launch_bounds__(256) void pack_nhwc_bf16(
    const float* __restrict__ inp, const float* __restrict__ ker,
    float* __restrict__ wsp)
{
    unsigned* wsu = (unsigned*)wsp;
    const int t = threadIdx.x;
    const int e = blockIdx.x * 256 + t;     // flat pixel (b*HW + hw)
    const int b = e >> 16;
    const int hw = e & (HW_ - 1);
    const float* src = inp + (size_t)b * (C_ * HW_) + hw;
    float v[C_];
#pragma unroll
    for (int c = 0; c < C_; c++)
        v[c] = src[c * HW_];                // coalesced per c-plane
    unsigned u[8];
#pragma unroll
    for (int j = 0; j < 8; j++)
        u[j] = rne_bf16(v[2 * j]) | (rne_bf16(v[2 * j + 1]) << 16);
    uint4* dst = ((uint4*)wsu) + (size_t)e * 2;   // 32 B per pixel
    dst[0] = make_uint4(u[0], u[1], u[2], u[3]);
    dst[1] = make_uint4(u[4], u[5], u[6], u[7]);

    if (blockIdx.x == 0) {
        // t_ker[kk*256 + c*16 + o] = ker[(o*16+c)*9 + kk]
        for (int i = t; i < KK_ * C_ * CO_; i += 256) {
            const int kk = i >> 8;
            const int c  = (i >> 4) & 15;
            const int o  = i & 15;
            wsp[KER_OFF + i] = ker[(o * C_ + c) * KK_ + kk];
        }
    }
}

// ------- tap address/weight setup ------------------------------------------
__device__ __forceinline__ void tap_setup(
    int h, int w, int kk, float dy, float dx,
    int* idx, float* wt)
{
    const float y = dy + (float)(h - 1 + kk / KS_);
    const float x = dx + (float)(w - 1 + kk % KS_);
    const float y0f = floorf(y);
    const float x0f = floorf(x);
    const int   y0  = (int)y0f;
    const int   x0  = (int)x0f;
    const float wy  = y - y0f;
    const float wx  = x - x0f;

    float w00 = (1.f - wy) * (1.f - wx);
    float w01 = (1.f - wy) * wx;
    float w10 = wy * (1.f - wx);
    float w11 = wy * wx;

    const bool v0y = ((unsigned)y0       < (unsigned)H_);
    const bool v1y = ((unsigned)(y0 + 1) < (unsigned)H_);
    const bool v0x = ((unsigned)x0       < (unsigned)W_);
    const bool v1x = ((unsigned)(x0 + 1) < (unsigned)W_);

    wt[0] = (v0y & v0x) ? w00 : 0.f;
    wt[1] = (v0y & v1x) ? w01 : 0.f;
    wt[2] = (v1y & v0x) ? w10 : 0.f;
    wt[3] = (v1y & v1x) ? w11 : 0.f;

    const int y0c = min(max(y0,     0), H_ - 1);
    const int y1c = min(max(y0 + 1, 0), H_ - 1);
    const int x0c = min(max(x0,     0), W_ - 1);
    const int x1c = min(max(x0 + 1, 0), W_ - 1);

    idx[0] = y0c * W_ + x0c;
    idx[1] = y0c * W_ + x1c;
    idx[2] = y1c * W_ + x0c;
    idx[3] = y1c * W_ + x1c;
}

__device__ __forceinline__ void blend2(
    unsigned a, unsigned b, unsigned c, unsigned d,
    float w0, float w1, float w2, float w3, float* s)
{
    s[0] = w0 * LOBF(a) + w1 * LOBF(b) + w2 * LOBF(c) + w3 * LOBF(d);
    s[1] = w0 * HIBF(a) + w1 * HIBF(b) + w2 * HIBF(c) + w3 * HIBF(d);
}

// ------- Kernel 2: deform-conv + MSE, bf16 NHWC, SGPR weights, pipelined ---
__global__ __launch_bounds__(256, 4) void deform_loss_bf16(
    const float* __restrict__ off, const float* __restrict__ wsp,
    const float* __restrict__ tgt, float* __restrict__ out)
{
    // XCD swizzle: bijection on [0,1024); xcd = blk&7 gets 128 contiguous
    // rows of one image -> per-XCD L2 locality (round-4 verified: 26 MB fetch)
    const int bh = (blockIdx.x & 7) * 128 + (blockIdx.x >> 3);
    const int b  = bh >> 8;
    const int h  = bh & (H_ - 1);
    const int w  = threadIdx.x;
    const int hw = h * W_ + w;

    const float* offb = off + (size_t)b * (2 * KK_ * HW_) + hw;
    const uint4* ib   = ((const uint4*)wsp) + (size_t)b * HW_ * 2;
    const float* tker = wsp + KER_OFF;

    float acc[CO_];
#pragma unroll
    for (int o = 0; o < CO_; o++) acc[o] = 0.f;

    int   idx[4];
    float wt[4];
    uint4 A0, A1, B0, B1, Cc0, Cc1, D0, D1;   // current tap's 4 corners (bf16)

    // prologue: tap 0 loads
    {
        const float dy = offb[0];
        const float dx = offb[HW_];
        tap_setup(h, w, 0, dy, dx, idx, wt);
        A0 = ib[idx[0] * 2]; A1 = ib[idx[0] * 2 + 1];
        B0 = ib[idx[1] * 2]; B1 = ib[idx[1] * 2 + 1];
        Cc0 = ib[idx[2] * 2]; Cc1 = ib[idx[2] * 2 + 1];
        D0 = ib[idx[3] * 2]; D1 = ib[idx[3] * 2 + 1];
    }

#pragma unroll 1
    for (int kk = 0; kk < KK_; kk++) {
        float dyN = 0.f, dxN = 0.f;
        if (kk + 1 < KK_) {
            dyN = offb[(2 * kk + 2) * HW_];
            dxN = offb[(2 * kk + 3) * HW_];
        }

        // consume: unpack bf16 + bilinear blend -> sc[16]
        float sc[C_];
        blend2(A0.x, B0.x, Cc0.x, D0.x, wt[0], wt[1], wt[2], wt[3], sc + 0);
        blend2(A0.y, B0.y, Cc0.y, D0.y, wt[0], wt[1], wt[2], wt[3], sc + 2);
        blend2(A0.z, B0.z, Cc0.z, D0.z, wt[0], wt[1], wt[2], wt[3], sc + 4);
        blend2(A0.w, B0.w, Cc0.w, D0.w, wt[0], wt[1], wt[2], wt[3], sc + 6);
        blend2(A1.x, B1.x, Cc1.x, D1.x, wt[0], wt[1], wt[2], wt[3], sc + 8);
        blend2(A1.y, B1.y, Cc1.y, D1.y, wt[0], wt[1], wt[2], wt[3], sc + 10);
        blend2(A1.z, B1.z, Cc1.z, D1.z, wt[0], wt[1], wt[2], wt[3], sc + 12);
        blend2(A1.w, B1.w, Cc1.w, D1.w, wt[0], wt[1], wt[2], wt[3], sc + 14);

        // prefetch tap kk+1 (in flight during the 256-FMA block below)
        if (kk + 1 < KK_) {
            tap_setup(h, w, kk + 1, dyN, dxN, idx, wt);
            A0 = ib[idx[0] * 2]; A1 = ib[idx[0] * 2 + 1];
            B0 = ib[idx[1] * 2]; B1 = ib[idx[1] * 2 + 1];
            Cc0 = ib[idx[2] * 2]; Cc1 = ib[idx[2] * 2 + 1];
            D0 = ib[idx[3] * 2]; D1 = ib[idx[3] * 2 + 1];
        }

        // accumulate: kt is wave-uniform -> s_load broadcasts, FMA w/ SGPR
        const float* kt = tker + kk * (C_ * CO_);
#pragma unroll
        for (int c = 0; c < C_; c++) {
            const float s = sc[c];
#pragma unroll
            for (int o = 0; o < CO_; o++)
                acc[o] = fmaf(s, kt[c * 16 + o], acc[o]);
        }
    }

    const float* tb = tgt + (size_t)b * (CO_ * HW_) + hw;
    float part = 0.f;
#pragma unroll
    for (int o = 0; o < CO_; o++) {
        const float d = acc[o] - tb[o * HW_];
        part = fmaf(d, d, part);
    }
    part *= (1.0f / (float)((size_t)B_ * CO_ * HW_));

#pragma unroll
    for (int sft = 32; sft > 0; sft >>= 1)
        part += __shfl_down(part, sft, 64);
    if ((threadIdx.x & 63) == 0)
        atomicAdd(out, part);
}

// ------- Fallback (round-1 NCHW kernel, used if ws too small) --------------
__global__ __launch_bounds__(256) void deform_loss_kernel(
    const float* __restrict__ off, const float* __restrict__ inp,
    const float* __restrict__ ker, const float* __restrict__ tgt,
    float* __restrict__ out)
{
    const int idx = blockIdx.x * blockDim.x + threadIdx.x;
    float part = 0.f;
    if (idx < B_ * H_ * W_) {
        const int w  = idx & (W_ - 1);
        const int h  = (idx >> 8) & (H_ - 1);
        const int b  = idx >> 16;
        const int hw = h * W_ + w;
        const float* offb = off + (size_t)b * (2 * KK_ * HW_);
        const float* inpb = inp + (size_t)b * (C_ * HW_);
        float acc[CO_];
#pragma unroll
        for (int o = 0; o < CO_; o++) acc[o] = 0.f;
        for (int kk = 0; kk < KK_; kk++) {
            const float dy = offb[(2 * kk)     * HW_ + hw];
            const float dx = offb[(2 * kk + 1) * HW_ + hw];
            const float y = dy + (float)(h - 1 + kk / KS_);
            const float x = dx + (float)(w - 1 + kk % KS_);
            const float y0f = floorf(y);
            const float x0f = floorf(x);
            const int   y0  = (int)y0f;
            const int   x0  = (int)x0f;
            const float wy  = y - y0f;
            const float wx  = x - x0f;
            float w00 = (1.f - wy) * (1.f - wx);
            float w01 = (1.f - wy) * wx;
            float w10 = wy * (1.f - wx);
            float w11 = wy * wx;
            const bool v0y = ((unsigned)y0       < (unsigned)H_);
            const bool v1y = ((unsigned)(y0 + 1) < (unsigned)H_);
            const bool v0x = ((unsigned)x0       < (unsigned)W_);
            const bool v1x = ((unsigned)(x0 + 1) < (unsigned)W_);
            w00 = (v0y & v0x) ? w00 : 0.f;
            w01 = (v0y & v1x) ? w01 : 0.f;
            w10 = (v1y & v0x) ? w10 : 0.f;
            w11 = (v1y & v1x) ? w11 : 0.f;
            const int i00 = min(max(y0,0),H_-1)*W_ + min(max(x0,0),W_-1);
            const int i01 = min(max(y0,0),H_-1)*W_ + min(max(x0+1,0),W_-1);
            const int i10 = min(max(y0+1,0),H_-1)*W_ + min(max(x0,0),W_-1);
            const int i11 = min(max(y0+1,0),H_-1)*W_ + min(max(x0+1,0),W_-1);
            for (int c = 0; c < C_; c++) {
                const float* pp = inpb + c * HW_;
                const float s = pp[i00]*w00 + pp[i01]*w01 + pp[i10]*w10 + pp[i11]*w11;
#pragma unroll
                for (int o = 0; o < CO_; o++)
                    acc[o] = fmaf(s, ker[(o * C_ + c) * KK_ + kk], acc[o]);
            }
        }
        const float* tb = tgt + (size_t)b * (CO_ * HW_);
#pragma unroll
        for (int o = 0; o < CO_; o++) {
            const float d = acc[o] - tb[o * HW_ + hw];
            part = fmaf(d, d, part);
        }
        part *= (1.0f / (float)((size_t)B_ * CO_ * HW_));
    }
#pragma unroll
    for (int sft = 32; sft > 0; sft >>= 1)
        part += __shfl_down(part, sft, 64);
    if ((threadIdx.x & 63) == 0)
        atomicAdd(out, part);
}

extern "C" void kernel_launch(void* const* d_in, const int* in_sizes, int n_in,
                              void* d_out, int out_size, void* d_ws, size_t ws_size,
                              hipStream_t stream) {
    const float* offsets = (const float*)d_in[0];
    const float* input   = (const float*)d_in[1];
    const float* ker     = (const float*)d_in[2];
    const float* target  = (const float*)d_in[3];
    float* out = (float*)d_out;

    hipMemsetAsync(out, 0, sizeof(float), stream);

    const size_t need = (KER_OFF + (size_t)KK_ * C_ * CO_) * sizeof(float);
    if (ws_size >= need) {
        float* wsp = (float*)d_ws;
        pack_nhwc_bf16<<<(B_ * HW_) / 256, 256, 0, stream>>>(input, ker, wsp);
        deform_loss_bf16<<<B_ * H_, 256, 0, stream>>>(offsets, wsp, target, out);
    } else {
        const int total = B_ * H_ * W_;
        deform_loss_kernel<<<(total + 255) / 256, 256, 0, stream>>>(
            offsets, input, ker, target, out);
    }
}